// Round 19
// baseline (55.226 us; speedup 1.0000x reference)
//
#include <hip/hip_runtime.h>
#include <hip/hip_bf16.h>

// B=8, S=2048, D_MODEL=1024, D_K=D_V=64, causal, fp32 in/out.
// ws (u16 units): Qb[16384*64] | Kb[16384*64] | Vt[8*64*2048] | Wb[192*1024]
//                | Opart u16[1024*128*64] | Lpart f32[1024*128]

typedef __attribute__((ext_vector_type(4))) float f32x4;
typedef __attribute__((ext_vector_type(8))) short short8;
typedef __attribute__((ext_vector_type(4))) short short4v;

#define MFMA16(a, b, c) __builtin_amdgcn_mfma_f32_16x16x32_bf16((a), (b), (c), 0, 0, 0)

__device__ __forceinline__ unsigned short f2bf(float f) {
    unsigned int u = __float_as_uint(f);
    unsigned int r = (u + 0x7FFFu + ((u >> 16) & 1u)) >> 16;
    return (unsigned short)r;
}
__device__ __forceinline__ float bf2f(unsigned short u) {
    return __uint_as_float(((unsigned int)u) << 16);
}
__device__ __forceinline__ unsigned int cvtpk2(float lo, float hi) {
    unsigned int r;
    asm("v_cvt_pk_bf16_f32 %0, %1, %2" : "=v"(r) : "v"(lo), "v"(hi));
    return r;
}
__device__ __forceinline__ f32x4 zero4() {
    f32x4 z = {0.f, 0.f, 0.f, 0.f};
    return z;
}
__device__ __forceinline__ void async16(const unsigned short* gsrc, unsigned short* ldst) {
    __builtin_amdgcn_global_load_lds(
        (const __attribute__((address_space(1))) unsigned int*)gsrc,
        (__attribute__((address_space(3))) unsigned int*)ldst, 16, 0, 0);
}

// ---------------------------------------------------------------------------
// Kernel 0: W_Q|W_K|W_V fp32[64][1024] -> Wb bf16[192][1024]
// ---------------------------------------------------------------------------
__global__ __launch_bounds__(256) void wconv(
    const float* __restrict__ wq, const float* __restrict__ wk,
    const float* __restrict__ wv, unsigned short* __restrict__ Wb)
{
    const int idx = (blockIdx.x * 256 + threadIdx.x) * 8;
    const int r = idx >> 10, c = idx & 1023;
    const float* src = (r < 64)  ? (wq + (long)r * 1024 + c)
                     : (r < 128) ? (wk + (long)(r - 64) * 1024 + c)
                     :             (wv + (long)(r - 128) * 1024 + c);
    f32x4 v0 = *(const f32x4*)src;
    f32x4 v1 = *(const f32x4*)(src + 4);
    short8 o;
    ((unsigned int*)&o)[0] = cvtpk2(v0[0], v0[1]);
    ((unsigned int*)&o)[1] = cvtpk2(v0[2], v0[3]);
    ((unsigned int*)&o)[2] = cvtpk2(v1[0], v1[1]);
    ((unsigned int*)&o)[3] = cvtpk2(v1[2], v1[3]);
    *(short8*)(Wb + idx) = o;
}

// ---------------------------------------------------------------------------
// Kernel 1: QKV GEMM v5 — R13 schedule, REAL occupancy x2.
// BM=32, BN=96 (col-half per block), BK=64. 256 thr = 4 waves (2 rowgroups
// x 2 colgroups; wave tile 16x48, acc[3]). Grid 1024 = 512 rowtiles x 2
// colhalves -> 4 blocks/CU, 4 waves/SIMD (vs 2 before). LDS 32KB: B dbuf
// 2x12KB (12 async16/block, 3/wave), A dbuf 2x4KB (R13 staging map).
// Counted vmcnt: issue {3 B + 2 A} per iter; post-compute vmcnt(2).
// ---------------------------------------------------------------------------
__global__ __launch_bounds__(256, 4) void qkv_gemm(
    const float* __restrict__ x,
    const unsigned short* __restrict__ Wb,
    unsigned short* __restrict__ Qb,
    unsigned short* __restrict__ Kb,
    unsigned short* __restrict__ Vt)
{
    __shared__ __align__(16) unsigned short Blds[2][96 * 64];   // 12KB each
    __shared__ __align__(16) unsigned short Alds[2][32 * 64];   //  4KB each

    const int tid  = threadIdx.x;
    const int lane = tid & 63;
    const int wid  = tid >> 6;          // 0..3
    const int c16  = lane & 15;
    const int g    = lane >> 4;
    const int rg   = wid >> 1;          // 0..1 row group (16 rows)
    const int cg   = wid & 1;           // 0..1 col group (48 cols)
    const int bx   = blockIdx.x;
    const int ch   = bx & 1;            // col half: global cols ch*96+..
    const long m0  = (long)(bx >> 1) * 32;

    // B staging: 96 rows x 128B, 12 async16 (3 per wave, 8 rows each)
    const int o0    = wid * 3072 + lane * 16;
    const int brow0 = o0 >> 7;                    // wid*24 + (lane>>3)
    const int boff0 = o0 & 127;                   // (lane&7)*16
    const unsigned short* bsrc0 =
        Wb + (long)(ch * 96 + brow0) * 1024 + ((boff0 ^ ((brow0 & 7) << 4)) >> 1);
    // i: +8 rows (row&7 invariant) -> src += 8192 u16, dst += 512 u16

    // A staging (R13 map): ar = tid>>3 (0..31), ac = tid&7 (8-float chunk)
    const int ar = tid >> 3, ac = tid & 7;
    const float* asrc = x + (m0 + ar) * 1024 + ac * 8;
    const int aoff = ar * 64 + (((ac * 16) ^ ((ar & 7) << 4)) >> 1);

    f32x4 acc[3];
    acc[0] = zero4(); acc[1] = zero4(); acc[2] = zero4();

    f32x4 na0, na1;

#define ISSUEB(K0, BUF) do {                                                   \
    _Pragma("unroll")                                                          \
    for (int i = 0; i < 3; ++i)                                                \
        async16(bsrc0 + (K0) + i * 8192, &Blds[BUF][wid * 1536 + i * 512]);    \
} while (0)

    // ---- prologue ----
    {
        f32x4 pa0 = *(const f32x4*)asrc;
        f32x4 pa1 = *(const f32x4*)(asrc + 4);
        ISSUEB(0, 0);
        na0 = *(const f32x4*)(asrc + 64);
        na1 = *(const f32x4*)(asrc + 68);
        short8 p;
        ((unsigned int*)&p)[0] = cvtpk2(pa0[0], pa0[1]);
        ((unsigned int*)&p)[1] = cvtpk2(pa0[2], pa0[3]);
        ((unsigned int*)&p)[2] = cvtpk2(pa1[0], pa1[1]);
        ((unsigned int*)&p)[3] = cvtpk2(pa1[2], pa1[3]);
        *(short8*)&Alds[0][aoff] = p;
        asm volatile("s_waitcnt vmcnt(2)" ::: "memory");   // pa + B(0) done; na fly
        asm volatile("s_waitcnt lgkmcnt(0)" ::: "memory");
        __builtin_amdgcn_s_barrier();
    }

    #pragma unroll 2
    for (int it = 0; it < 16; ++it) {
        const int cur = it & 1, nxt = cur ^ 1;
        const int kb = min(it + 1, 15) * 64;
        ISSUEB(kb, nxt);                               // +3
        const int ka = min(it + 2, 15) * 64;
        f32x4 qa0 = *(const f32x4*)(asrc + ka);        // +2
        f32x4 qa1 = *(const f32x4*)(asrc + ka + 4);
        // ---- compute on cur: wave tile 16 x 48 ----
        #pragma unroll
        for (int kc = 0; kc < 2; ++kc) {
            const int q = kc * 64 + g * 16;
            short8 af, bf[3];
            {
                const int rm = rg * 16 + c16;
                af = *(const short8*)&Alds[cur][rm * 64 + ((q ^ ((rm & 7) << 4)) >> 1)];
            }
            #pragma unroll
            for (int nt = 0; nt < 3; ++nt) {
                const int rb = cg * 48 + nt * 16 + c16;
                bf[nt] = *(const short8*)&Blds[cur][rb * 64 + ((q ^ ((rb & 7) << 4)) >> 1)];
            }
            __builtin_amdgcn_s_setprio(1);
            #pragma unroll
            for (int nt = 0; nt < 3; ++nt)
                acc[nt] = MFMA16(af, bf[nt], acc[nt]);
            __builtin_amdgcn_s_setprio(0);
        }
        // ---- stage A(it+1); counted drain (qa stays in flight) ----
        {
            short8 p;
            ((unsigned int*)&p)[0] = cvtpk2(na0[0], na0[1]);
            ((unsigned int*)&p)[1] = cvtpk2(na0[2], na0[3]);
            ((unsigned int*)&p)[2] = cvtpk2(na1[0], na1[1]);
            ((unsigned int*)&p)[3] = cvtpk2(na1[2], na1[3]);
            asm volatile("s_waitcnt vmcnt(2)" ::: "memory");  // na + B(nxt) done
            *(short8*)&Alds[nxt][aoff] = p;
            asm volatile("s_waitcnt lgkmcnt(0)" ::: "memory");
            __builtin_amdgcn_s_barrier();
            na0 = qa0; na1 = qa1;
        }
    }
#undef ISSUEB

    // ---- epilogue: D layout col=c16, row=g*4+r ----
    const long bb = m0 >> 11;
    {
        const long mrow = m0 + rg * 16 + g * 4;
        const long ss = mrow & 2047;
        #pragma unroll
        for (int nt = 0; nt < 3; ++nt) {
            const int n = ch * 96 + cg * 48 + nt * 16 + c16;
            if (n < 64) {
                #pragma unroll
                for (int r = 0; r < 4; ++r)
                    Qb[(mrow + r) * 64 + n] = f2bf(acc[nt][r]);
            } else if (n < 128) {
                #pragma unroll
                for (int r = 0; r < 4; ++r)
                    Kb[(mrow + r) * 64 + (n - 64)] = f2bf(acc[nt][r]);
            } else {
                short4v pv = { (short)f2bf(acc[nt][0]), (short)f2bf(acc[nt][1]),
                               (short)f2bf(acc[nt][2]), (short)f2bf(acc[nt][3]) };
                *(short4v*)&Vt[((bb * 64) + (n - 128)) * 2048 + ss] = pv;
            }
        }
    }
}

// ---------------------------------------------------------------------------
// Kernel 2a: attention partials (frozen from round 15).
// ---------------------------------------------------------------------------
__global__ __launch_bounds__(256, 4) void attn_part(
    const unsigned short* __restrict__ Qb,
    const unsigned short* __restrict__ Kb,
    const unsigned short* __restrict__ Vt,
    unsigned short* __restrict__ Opart,
    float* __restrict__ Lpart)
{
    __shared__ __align__(16) unsigned short Klds[3][32 * 64];
    __shared__ __align__(16) unsigned short Vlds[3][64 * 32];

    const int tid  = threadIdx.x;
    const int lane = tid & 63;
    const int wid  = tid >> 6;
    const int c16  = lane & 15;
    const int g    = lane >> 4;
    const int bidx = blockIdx.x;
    const int b    = bidx & 7;
    const int e    = (bidx >> 3) & 7;
    const int th   = bidx >> 6;
    const int T    = 7 - (th >> 1);
    const int h    = th & 1;

    const int steps = T + 1;
    const int kvb0  = e * steps;
    const int q0w   = T * 256 + h * 128 + wid * 32;
    const int u     = ((b * 8 + T) * 2 + h) * 8 + e;

    const unsigned short* Qbase = Qb + (long)b * 2048 * 64;
    const unsigned short* Kbase = Kb + (long)b * 2048 * 64;
    const unsigned short* Vbase = Vt + (long)b * 64 * 2048;
    const float SCL = 0.18033688f;

    const bool isK  = (wid < 2);
    const int krow0 = (wid * 16) + (lane >> 3);
    const int kswz  = (((lane & 7) * 16) ^ ((krow0 & 7) << 4)) >> 1;
    const int vj0   = ((wid - 2) * 2) * 64 + lane;
    const int vrow0 = vj0 >> 2;
    const int vswz  = ((((vj0 & 3) * 16) ^ ((vrow0 & 6) << 3)) >> 1);

#define STAGE(S, BUF) do {                                                     \
    const int _kv0s = (kvb0 + (S)) * 32;                                       \
    if (isK) {                                                                 \
        async16(Kbase + (long)(_kv0s + krow0) * 64 + kswz,                     \
                &Klds[BUF][wid * 1024]);                                       \
        async16(Kbase + (long)(_kv0s + krow0 + 8) * 64 + kswz,                 \
                &Klds[BUF][wid * 1024 + 512]);                                 \
    } else {                                                                   \
        async16(Vbase + (long)vrow0 * 2048 + _kv0s + vswz,                     \
                &Vlds[BUF][(wid - 2) * 1024]);                                 \
        async16(Vbase + (long)(vrow0 + 16) * 2048 + _kv0s + vswz,              \
                &Vlds[BUF][(wid - 2) * 1024 + 512]);                           \
    }                                                                          \
} while (0)

    short8 qf[2][2];
    int qgl[2];
    #pragma unroll
    for (int qg = 0; qg < 2; ++qg) {
        const unsigned short* qrow = Qbase + (long)(q0w + qg * 16 + c16) * 64;
        qf[qg][0] = *(const short8*)(qrow + g * 8);
        qf[qg][1] = *(const short8*)(qrow + 32 + g * 8);
        qgl[qg]   = q0w + qg * 16 + c16;
    }

    f32x4 acc[2][4];
    #pragma unroll
    for (int qg = 0; qg < 2; ++qg)
        #pragma unroll
        for (int vt = 0; vt < 4; ++vt) acc[qg][vt] = zero4();
    f32x4 lp4[2];
    lp4[0] = zero4(); lp4[1] = zero4();

    STAGE(0, 0);
    STAGE(min(1, steps - 1), 1);
    asm volatile("s_waitcnt vmcnt(2)" ::: "memory");
    __builtin_amdgcn_s_barrier();

    int cur = 0;
    for (int s = 0; s < steps; ++s) {
        {
            int bn = cur + 2; if (bn >= 3) bn -= 3;
            STAGE(min(s + 2, steps - 1), bn);
        }
        const int kv0 = (kvb0 + s) * 32;

        short8 vf[4];
        #pragma unroll
        for (int vt = 0; vt < 4; ++vt) {
            const int row = vt * 16 + c16;
            const char* vr = (const char*)&Vlds[cur][row * 32];
            const int xo = (row & 6) << 3;
            ((short4v*)&vf[vt])[0] = *(const short4v*)(vr + ((8 * g) ^ xo));
            ((short4v*)&vf[vt])[1] = *(const short4v*)(vr + ((32 + 8 * g) ^ xo));
        }
        f32x4 s2[2][2];
        #pragma unroll
        for (int nt = 0; nt < 2; ++nt) {
            const int row = nt * 16 + c16;
            const char* kr = (const char*)&Klds[cur][row * 64];
            const int xo = (row & 7) << 4;
            short8 kf0 = *(const short8*)(kr + ((g * 16) ^ xo));
            short8 kf1 = *(const short8*)(kr + ((64 + g * 16) ^ xo));
            __builtin_amdgcn_s_setprio(1);
            #pragma unroll
            for (int qg = 0; qg < 2; ++qg) {
                f32x4 z = zero4();
                z = MFMA16(kf0, qf[qg][0], z);
                z = MFMA16(kf1, qf[qg][1], z);
                s2[qg][nt] = z;
            }
            __builtin_amdgcn_s_setprio(0);
        }
        short8 af[2];
        #pragma unroll
        for (int qg = 0; qg < 2; ++qg) {
            #pragma unroll
            for (int nt = 0; nt < 2; ++nt) {
                float p[4];
                #pragma unroll
                for (int r = 0; r < 4; ++r) {
                    float v = exp2f(s2[qg][nt][r] * SCL);
                    const int kvg = kv0 + nt * 16 + g * 4 + r;
                    v = (kvg > qgl[qg]) ? 0.f : v;
                    lp4[qg][r] += v;
                    p[r] = v;
                }
                ((unsigned int*)&af[qg])[nt * 2]     = cvtpk2(p[0], p[1]);
                ((unsigned int*)&af[qg])[nt * 2 + 1] = cvtpk2(p[2], p[3]);
            }
        }
        __builtin_amdgcn_s_setprio(1);
        #pragma unroll
        for (int qg = 0; qg < 2; ++qg)
            #pragma unroll
            for (int vt = 0; vt < 4; ++vt)
                acc[qg][vt] = MFMA16(af[qg], vf[vt], acc[qg][vt]);
        __builtin_amdgcn_s_setprio(0);

        asm volatile("s_waitcnt vmcnt(2)" ::: "memory");
        __builtin_amdgcn_s_barrier();
        cur = (cur == 2) ? 0 : cur + 1;
    }
#undef STAGE

    #pragma unroll
    for (int qg = 0; qg < 2; ++qg) {
        float lpf = (lp4[qg][0] + lp4[qg][1]) + (lp4[qg][2] + lp4[qg][3]);
        lpf += __shfl_xor(lpf, 16);
        lpf += __shfl_xor(lpf, 32);
        if (g == 0)
            Lpart[u * 128 + wid * 32 + qg * 16 + c16] = lpf;
    }
    #pragma unroll
    for (int qg = 0; qg < 2; ++qg)
        #pragma unroll
        for (int vt = 0; vt < 4; ++vt)
            #pragma unroll
            for (int r = 0; r < 4; ++r) {
                const int row = wid * 32 + qg * 16 + g * 4 + r;
                Opart[((long)u * 128 + row) * 64 + vt * 16 + c16] =
                    f2bf(acc[qg][vt][r]);
            }
}

// ---------------------------------------------------------------------------
// Kernel 2b: merge 8 kv-eighth partials per row, normalize, write out.
// ---------------------------------------------------------------------------
__global__ __launch_bounds__(256) void attn_merge(
    const unsigned short* __restrict__ Opart,
    const float* __restrict__ Lpart,
    float* __restrict__ out)
{
    const int m    = blockIdx.x;
    const int bb   = m & 7;
    const int part = m >> 3;
    const int t    = threadIdx.x;
    const int lr   = part * 32 + (t >> 3);
    const int c8   = t & 7;
    const int T    = lr >> 8;
    const int wi   = lr & 255;
    const int h    = wi >> 7;
    const int ri   = wi & 127;
    const int ub   = ((bb * 8 + T) * 2 + h) * 8;

    float o[8];
    #pragma unroll
    for (int j = 0; j < 8; ++j) o[j] = 0.f;
    float l = 0.f;
    #pragma unroll
    for (int e = 0; e < 8; ++e) {
        const unsigned short* Op = Opart + ((long)(ub + e) * 128 + ri) * 64 + c8 * 8;
        short4v p0 = *(const short4v*)Op;
        short4v p1 = *(const short4v*)(Op + 4);
        #pragma unroll
        for (int j = 0; j < 4; ++j) {
            o[j]     += bf2f((unsigned short)p0[j]);
            o[4 + j] += bf2f((unsigned short)p1[j]);
        }
        l += Lpart[(ub + e) * 128 + ri];
    }
    const float inv = 1.0f / l;
    f32x4 o0 = { o[0] * inv, o[1] * inv, o[2] * inv, o[3] * inv };
    f32x4 o1 = { o[4] * inv, o[5] * inv, o[6] * inv, o[7] * inv };
    float* orow = out + ((long)bb * 2048 + lr) * 64 + c8 * 8;
    *(f32x4*)orow = o0;
    *(f32x4*)(orow + 4) = o1;
}

extern "C" void kernel_launch(void* const* d_in, const int* in_sizes, int n_in,
                              void* d_out, int out_size, void* d_ws, size_t ws_size,
                              hipStream_t stream)
{
    const float* x  = (const float*)d_in[0];
    const float* wq = (const float*)d_in[1];
    const float* wk = (const float*)d_in[2];
    const float* wv = (const float*)d_in[3];

    unsigned short* Qb    = (unsigned short*)d_ws;
    unsigned short* Kb    = Qb + (size_t)16384 * 64;
    unsigned short* Vt    = Kb + (size_t)16384 * 64;
    unsigned short* Wb    = Vt + (size_t)8 * 64 * 2048;
    unsigned short* Opart = Wb + (size_t)192 * 1024;
    float*          Lpart = (float*)(Opart + (size_t)1024 * 128 * 64);
    float* out = (float*)d_out;

    wconv<<<dim3(96), dim3(256), 0, stream>>>(wq, wk, wv, Wb);
    qkv_gemm<<<dim3(1024), dim3(256), 0, stream>>>(x, Wb, Qb, Kb, Vt);
    attn_part<<<dim3(1024), dim3(256), 0, stream>>>(Qb, Kb, Vt, Opart, Lpart);
    attn_merge<<<dim3(512), dim3(256), 0, stream>>>(Opart, Lpart, out);
}

// Round 20
// 46.141 us; speedup vs baseline: 1.1969x; 1.1969x over previous
//
#include <hip/hip_runtime.h>
#include <hip/hip_bf16.h>

// B=8, S=2048, D_MODEL=1024, D_K=D_V=64, causal, fp32 in/out.
// ws (u16 units): Qb[16384*64] | Kb[16384*64] | Vt[8*64*2048] | Wb[192*1024]
//                | Opart u16[1024*128*64] | Lpart f32[1024*128]

typedef __attribute__((ext_vector_type(4))) float f32x4;
typedef __attribute__((ext_vector_type(8))) short short8;
typedef __attribute__((ext_vector_type(4))) short short4v;

#define MFMA16(a, b, c) __builtin_amdgcn_mfma_f32_16x16x32_bf16((a), (b), (c), 0, 0, 0)

__device__ __forceinline__ unsigned short f2bf(float f) {
    unsigned int u = __float_as_uint(f);
    unsigned int r = (u + 0x7FFFu + ((u >> 16) & 1u)) >> 16;
    return (unsigned short)r;
}
__device__ __forceinline__ float bf2f(unsigned short u) {
    return __uint_as_float(((unsigned int)u) << 16);
}
__device__ __forceinline__ unsigned int cvtpk2(float lo, float hi) {
    unsigned int r;
    asm("v_cvt_pk_bf16_f32 %0, %1, %2" : "=v"(r) : "v"(lo), "v"(hi));
    return r;
}
__device__ __forceinline__ f32x4 zero4() {
    f32x4 z = {0.f, 0.f, 0.f, 0.f};
    return z;
}
__device__ __forceinline__ void async16(const unsigned short* gsrc, unsigned short* ldst) {
    __builtin_amdgcn_global_load_lds(
        (const __attribute__((address_space(1))) unsigned int*)gsrc,
        (__attribute__((address_space(3))) unsigned int*)ldst, 16, 0, 0);
}

// ---------------------------------------------------------------------------
// Kernel 0: W_Q|W_K|W_V fp32[64][1024] -> Wb bf16[192][1024]
// ---------------------------------------------------------------------------
__global__ __launch_bounds__(256) void wconv(
    const float* __restrict__ wq, const float* __restrict__ wk,
    const float* __restrict__ wv, unsigned short* __restrict__ Wb)
{
    const int idx = (blockIdx.x * 256 + threadIdx.x) * 8;
    const int r = idx >> 10, c = idx & 1023;
    const float* src = (r < 64)  ? (wq + (long)r * 1024 + c)
                     : (r < 128) ? (wk + (long)(r - 64) * 1024 + c)
                     :             (wv + (long)(r - 128) * 1024 + c);
    f32x4 v0 = *(const f32x4*)src;
    f32x4 v1 = *(const f32x4*)(src + 4);
    short8 o;
    ((unsigned int*)&o)[0] = cvtpk2(v0[0], v0[1]);
    ((unsigned int*)&o)[1] = cvtpk2(v0[2], v0[3]);
    ((unsigned int*)&o)[2] = cvtpk2(v1[0], v1[1]);
    ((unsigned int*)&o)[3] = cvtpk2(v1[2], v1[3]);
    *(short8*)(Wb + idx) = o;
}

// ---------------------------------------------------------------------------
// Kernel 1: QKV GEMM (R13/R15-best schedule). BM=32, BN=192, BK=64, dbuf
// LDS, 256 thr, grid 512; A depth-2 reg prefetch + counted vmcnt(2).
// R20 change (index-only): XCD-LOCAL row map — b = bx&7, t = bx>>3,
// m0 = (b*64+t)*32, so batch-b outputs are written from XCD b and
// attn_part (block b = bidx&7) reads them from its local L2.
// ---------------------------------------------------------------------------
__global__ __launch_bounds__(256, 2) void qkv_gemm(
    const float* __restrict__ x,
    const unsigned short* __restrict__ Wb,
    unsigned short* __restrict__ Qb,
    unsigned short* __restrict__ Kb,
    unsigned short* __restrict__ Vt)
{
    __shared__ __align__(16) unsigned short Blds[2][192 * 64];
    __shared__ __align__(16) unsigned short Alds[2][32 * 64];

    const int tid  = threadIdx.x;
    const int lane = tid & 63;
    const int wid  = tid >> 6;
    const int c16  = lane & 15;
    const int g    = lane >> 4;
    const int bx   = blockIdx.x;
    const long m0  = (long)((bx & 7) * 64 + (bx >> 3)) * 32;   // XCD-local

    const int o0    = wid * 6144 + lane * 16;
    const int brow0 = o0 >> 7;
    const int boff0 = o0 & 127;
    const unsigned short* bsrc0 =
        Wb + (long)brow0 * 1024 + ((boff0 ^ ((brow0 & 7) << 4)) >> 1);

    const int ar  = tid >> 3, acq = tid & 7;
    const float* asrc = x + (m0 + ar) * 1024 + acq * 8;
    const int aoff = ar * 64 + (((acq * 16) ^ ((ar & 7) << 4)) >> 1);

    f32x4 acc[2][3];
    #pragma unroll
    for (int i = 0; i < 2; ++i)
        #pragma unroll
        for (int j = 0; j < 3; ++j) acc[i][j] = zero4();

    f32x4 na0, na1;
    {
        f32x4 pa0 = *(const f32x4*)asrc;
        f32x4 pa1 = *(const f32x4*)(asrc + 4);
        #pragma unroll
        for (int i = 0; i < 6; ++i)
            async16(bsrc0 + i * 8192, &Blds[0][wid * 3072 + i * 512]);
        na0 = *(const f32x4*)(asrc + 64);
        na1 = *(const f32x4*)(asrc + 68);
        short8 p;
        ((unsigned int*)&p)[0] = cvtpk2(pa0[0], pa0[1]);
        ((unsigned int*)&p)[1] = cvtpk2(pa0[2], pa0[3]);
        ((unsigned int*)&p)[2] = cvtpk2(pa1[0], pa1[1]);
        ((unsigned int*)&p)[3] = cvtpk2(pa1[2], pa1[3]);
        *(short8*)&Alds[0][aoff] = p;
        asm volatile("s_waitcnt vmcnt(2)" ::: "memory");
        asm volatile("s_waitcnt lgkmcnt(0)" ::: "memory");
        __builtin_amdgcn_s_barrier();
    }

    #pragma unroll 2
    for (int it = 0; it < 16; ++it) {
        const int cur = it & 1, nxt = cur ^ 1;
        const int kb = min(it + 1, 15) * 64;
        #pragma unroll
        for (int i = 0; i < 6; ++i)
            async16(bsrc0 + kb + i * 8192, &Blds[nxt][wid * 3072 + i * 512]);
        const int ka = min(it + 2, 15) * 64;
        f32x4 qa0 = *(const f32x4*)(asrc + ka);
        f32x4 qa1 = *(const f32x4*)(asrc + ka + 4);
        #pragma unroll
        for (int kc = 0; kc < 2; ++kc) {
            const int q = kc * 64 + g * 16;
            short8 af[2], bf[3];
            #pragma unroll
            for (int mt = 0; mt < 2; ++mt) {
                const int rm = mt * 16 + c16;
                af[mt] = *(const short8*)&Alds[cur][rm * 64 + ((q ^ ((rm & 7) << 4)) >> 1)];
            }
            #pragma unroll
            for (int nt = 0; nt < 3; ++nt) {
                const int rb = wid * 48 + nt * 16 + c16;
                bf[nt] = *(const short8*)&Blds[cur][rb * 64 + ((q ^ ((rb & 7) << 4)) >> 1)];
            }
            __builtin_amdgcn_s_setprio(1);
            #pragma unroll
            for (int mt = 0; mt < 2; ++mt)
                #pragma unroll
                for (int nt = 0; nt < 3; ++nt)
                    acc[mt][nt] = MFMA16(af[mt], bf[nt], acc[mt][nt]);
            __builtin_amdgcn_s_setprio(0);
        }
        {
            short8 p;
            ((unsigned int*)&p)[0] = cvtpk2(na0[0], na0[1]);
            ((unsigned int*)&p)[1] = cvtpk2(na0[2], na0[3]);
            ((unsigned int*)&p)[2] = cvtpk2(na1[0], na1[1]);
            ((unsigned int*)&p)[3] = cvtpk2(na1[2], na1[3]);
            asm volatile("s_waitcnt vmcnt(2)" ::: "memory");
            *(short8*)&Alds[nxt][aoff] = p;
            asm volatile("s_waitcnt lgkmcnt(0)" ::: "memory");
            __builtin_amdgcn_s_barrier();
            na0 = qa0; na1 = qa1;
        }
    }

    const long bb = m0 >> 11;
    #pragma unroll
    for (int mt = 0; mt < 2; ++mt) {
        const long mrow = m0 + mt * 16 + g * 4;
        const long ss = mrow & 2047;
        #pragma unroll
        for (int nt = 0; nt < 3; ++nt) {
            const int n = wid * 48 + nt * 16 + c16;
            if (n < 64) {
                #pragma unroll
                for (int r = 0; r < 4; ++r)
                    Qb[(mrow + r) * 64 + n] = f2bf(acc[mt][nt][r]);
            } else if (n < 128) {
                #pragma unroll
                for (int r = 0; r < 4; ++r)
                    Kb[(mrow + r) * 64 + (n - 64)] = f2bf(acc[mt][nt][r]);
            } else {
                short4v pv = { (short)f2bf(acc[mt][nt][0]), (short)f2bf(acc[mt][nt][1]),
                               (short)f2bf(acc[mt][nt][2]), (short)f2bf(acc[mt][nt][3]) };
                *(short4v*)&Vt[((bb * 64) + (n - 128)) * 2048 + ss] = pv;
            }
        }
    }
}

// ---------------------------------------------------------------------------
// Kernel 2a: attention partials (frozen from round 15).
// ---------------------------------------------------------------------------
__global__ __launch_bounds__(256, 4) void attn_part(
    const unsigned short* __restrict__ Qb,
    const unsigned short* __restrict__ Kb,
    const unsigned short* __restrict__ Vt,
    unsigned short* __restrict__ Opart,
    float* __restrict__ Lpart)
{
    __shared__ __align__(16) unsigned short Klds[3][32 * 64];
    __shared__ __align__(16) unsigned short Vlds[3][64 * 32];

    const int tid  = threadIdx.x;
    const int lane = tid & 63;
    const int wid  = tid >> 6;
    const int c16  = lane & 15;
    const int g    = lane >> 4;
    const int bidx = blockIdx.x;
    const int b    = bidx & 7;
    const int e    = (bidx >> 3) & 7;
    const int th   = bidx >> 6;
    const int T    = 7 - (th >> 1);
    const int h    = th & 1;

    const int steps = T + 1;
    const int kvb0  = e * steps;
    const int q0w   = T * 256 + h * 128 + wid * 32;
    const int u     = ((b * 8 + T) * 2 + h) * 8 + e;

    const unsigned short* Qbase = Qb + (long)b * 2048 * 64;
    const unsigned short* Kbase = Kb + (long)b * 2048 * 64;
    const unsigned short* Vbase = Vt + (long)b * 64 * 2048;
    const float SCL = 0.18033688f;

    const bool isK  = (wid < 2);
    const int krow0 = (wid * 16) + (lane >> 3);
    const int kswz  = (((lane & 7) * 16) ^ ((krow0 & 7) << 4)) >> 1;
    const int vj0   = ((wid - 2) * 2) * 64 + lane;
    const int vrow0 = vj0 >> 2;
    const int vswz  = ((((vj0 & 3) * 16) ^ ((vrow0 & 6) << 3)) >> 1);

#define STAGE(S, BUF) do {                                                     \
    const int _kv0s = (kvb0 + (S)) * 32;                                       \
    if (isK) {                                                                 \
        async16(Kbase + (long)(_kv0s + krow0) * 64 + kswz,                     \
                &Klds[BUF][wid * 1024]);                                       \
        async16(Kbase + (long)(_kv0s + krow0 + 8) * 64 + kswz,                 \
                &Klds[BUF][wid * 1024 + 512]);                                 \
    } else {                                                                   \
        async16(Vbase + (long)vrow0 * 2048 + _kv0s + vswz,                     \
                &Vlds[BUF][(wid - 2) * 1024]);                                 \
        async16(Vbase + (long)(vrow0 + 16) * 2048 + _kv0s + vswz,              \
                &Vlds[BUF][(wid - 2) * 1024 + 512]);                           \
    }                                                                          \
} while (0)

    short8 qf[2][2];
    int qgl[2];
    #pragma unroll
    for (int qg = 0; qg < 2; ++qg) {
        const unsigned short* qrow = Qbase + (long)(q0w + qg * 16 + c16) * 64;
        qf[qg][0] = *(const short8*)(qrow + g * 8);
        qf[qg][1] = *(const short8*)(qrow + 32 + g * 8);
        qgl[qg]   = q0w + qg * 16 + c16;
    }

    f32x4 acc[2][4];
    #pragma unroll
    for (int qg = 0; qg < 2; ++qg)
        #pragma unroll
        for (int vt = 0; vt < 4; ++vt) acc[qg][vt] = zero4();
    f32x4 lp4[2];
    lp4[0] = zero4(); lp4[1] = zero4();

    STAGE(0, 0);
    STAGE(min(1, steps - 1), 1);
    asm volatile("s_waitcnt vmcnt(2)" ::: "memory");
    __builtin_amdgcn_s_barrier();

    int cur = 0;
    for (int s = 0; s < steps; ++s) {
        {
            int bn = cur + 2; if (bn >= 3) bn -= 3;
            STAGE(min(s + 2, steps - 1), bn);
        }
        const int kv0 = (kvb0 + s) * 32;

        short8 vf[4];
        #pragma unroll
        for (int vt = 0; vt < 4; ++vt) {
            const int row = vt * 16 + c16;
            const char* vr = (const char*)&Vlds[cur][row * 32];
            const int xo = (row & 6) << 3;
            ((short4v*)&vf[vt])[0] = *(const short4v*)(vr + ((8 * g) ^ xo));
            ((short4v*)&vf[vt])[1] = *(const short4v*)(vr + ((32 + 8 * g) ^ xo));
        }
        f32x4 s2[2][2];
        #pragma unroll
        for (int nt = 0; nt < 2; ++nt) {
            const int row = nt * 16 + c16;
            const char* kr = (const char*)&Klds[cur][row * 64];
            const int xo = (row & 7) << 4;
            short8 kf0 = *(const short8*)(kr + ((g * 16) ^ xo));
            short8 kf1 = *(const short8*)(kr + ((64 + g * 16) ^ xo));
            __builtin_amdgcn_s_setprio(1);
            #pragma unroll
            for (int qg = 0; qg < 2; ++qg) {
                f32x4 z = zero4();
                z = MFMA16(kf0, qf[qg][0], z);
                z = MFMA16(kf1, qf[qg][1], z);
                s2[qg][nt] = z;
            }
            __builtin_amdgcn_s_setprio(0);
        }
        short8 af[2];
        #pragma unroll
        for (int qg = 0; qg < 2; ++qg) {
            #pragma unroll
            for (int nt = 0; nt < 2; ++nt) {
                float p[4];
                #pragma unroll
                for (int r = 0; r < 4; ++r) {
                    float v = exp2f(s2[qg][nt][r] * SCL);
                    const int kvg = kv0 + nt * 16 + g * 4 + r;
                    v = (kvg > qgl[qg]) ? 0.f : v;
                    lp4[qg][r] += v;
                    p[r] = v;
                }
                ((unsigned int*)&af[qg])[nt * 2]     = cvtpk2(p[0], p[1]);
                ((unsigned int*)&af[qg])[nt * 2 + 1] = cvtpk2(p[2], p[3]);
            }
        }
        __builtin_amdgcn_s_setprio(1);
        #pragma unroll
        for (int qg = 0; qg < 2; ++qg)
            #pragma unroll
            for (int vt = 0; vt < 4; ++vt)
                acc[qg][vt] = MFMA16(af[qg], vf[vt], acc[qg][vt]);
        __builtin_amdgcn_s_setprio(0);

        asm volatile("s_waitcnt vmcnt(2)" ::: "memory");
        __builtin_amdgcn_s_barrier();
        cur = (cur == 2) ? 0 : cur + 1;
    }
#undef STAGE

    #pragma unroll
    for (int qg = 0; qg < 2; ++qg) {
        float lpf = (lp4[qg][0] + lp4[qg][1]) + (lp4[qg][2] + lp4[qg][3]);
        lpf += __shfl_xor(lpf, 16);
        lpf += __shfl_xor(lpf, 32);
        if (g == 0)
            Lpart[u * 128 + wid * 32 + qg * 16 + c16] = lpf;
    }
    #pragma unroll
    for (int qg = 0; qg < 2; ++qg)
        #pragma unroll
        for (int vt = 0; vt < 4; ++vt)
            #pragma unroll
            for (int r = 0; r < 4; ++r) {
                const int row = wid * 32 + qg * 16 + g * 4 + r;
                Opart[((long)u * 128 + row) * 64 + vt * 16 + c16] =
                    f2bf(acc[qg][vt][r]);
            }
}

// ---------------------------------------------------------------------------
// Kernel 2b: merge 8 kv-eighth partials per row, normalize, write out.
// ---------------------------------------------------------------------------
__global__ __launch_bounds__(256) void attn_merge(
    const unsigned short* __restrict__ Opart,
    const float* __restrict__ Lpart,
    float* __restrict__ out)
{
    const int m    = blockIdx.x;
    const int bb   = m & 7;
    const int part = m >> 3;
    const int t    = threadIdx.x;
    const int lr   = part * 32 + (t >> 3);
    const int c8   = t & 7;
    const int T    = lr >> 8;
    const int wi   = lr & 255;
    const int h    = wi >> 7;
    const int ri   = wi & 127;
    const int ub   = ((bb * 8 + T) * 2 + h) * 8;

    float o[8];
    #pragma unroll
    for (int j = 0; j < 8; ++j) o[j] = 0.f;
    float l = 0.f;
    #pragma unroll
    for (int e = 0; e < 8; ++e) {
        const unsigned short* Op = Opart + ((long)(ub + e) * 128 + ri) * 64 + c8 * 8;
        short4v p0 = *(const short4v*)Op;
        short4v p1 = *(const short4v*)(Op + 4);
        #pragma unroll
        for (int j = 0; j < 4; ++j) {
            o[j]     += bf2f((unsigned short)p0[j]);
            o[4 + j] += bf2f((unsigned short)p1[j]);
        }
        l += Lpart[(ub + e) * 128 + ri];
    }
    const float inv = 1.0f / l;
    f32x4 o0 = { o[0] * inv, o[1] * inv, o[2] * inv, o[3] * inv };
    f32x4 o1 = { o[4] * inv, o[5] * inv, o[6] * inv, o[7] * inv };
    float* orow = out + ((long)bb * 2048 + lr) * 64 + c8 * 8;
    *(f32x4*)orow = o0;
    *(f32x4*)(orow + 4) = o1;
}

extern "C" void kernel_launch(void* const* d_in, const int* in_sizes, int n_in,
                              void* d_out, int out_size, void* d_ws, size_t ws_size,
                              hipStream_t stream)
{
    const float* x  = (const float*)d_in[0];
    const float* wq = (const float*)d_in[1];
    const float* wk = (const float*)d_in[2];
    const float* wv = (const float*)d_in[3];

    unsigned short* Qb    = (unsigned short*)d_ws;
    unsigned short* Kb    = Qb + (size_t)16384 * 64;
    unsigned short* Vt    = Kb + (size_t)16384 * 64;
    unsigned short* Wb    = Vt + (size_t)8 * 64 * 2048;
    unsigned short* Opart = Wb + (size_t)192 * 1024;
    float*          Lpart = (float*)(Opart + (size_t)1024 * 128 * 64);
    float* out = (float*)d_out;

    wconv<<<dim3(96), dim3(256), 0, stream>>>(wq, wk, wv, Wb);
    qkv_gemm<<<dim3(512), dim3(256), 0, stream>>>(x, Wb, Qb, Kb, Vt);
    attn_part<<<dim3(1024), dim3(256), 0, stream>>>(Qb, Kb, Vt, Opart, Lpart);
    attn_merge<<<dim3(512), dim3(256), 0, stream>>>(Opart, Lpart, out);
}